// Round 2
// baseline (1983.223 us; speedup 1.0000x reference)
//
#include <hip/hip_runtime.h>
#include <hip/hip_bf16.h>
#include <cstdint>
#include <cstddef>

#define HEADS 8
#define HID 64
#define HF 512              // HEADS*HID
#define NEG_SLOPE 0.2f
#define LN_EPS 1e-5f

typedef __hip_bfloat16 bf16;

// ---------------- helpers ---------------------------------------------------
__device__ __forceinline__ float wsum64(float v) {
#pragma unroll
  for (int o = 32; o > 0; o >>= 1) v += __shfl_xor(v, o, 64);
  return v;
}
__device__ __forceinline__ float leaky(float v) { return v >= 0.f ? v : NEG_SLOPE * v; }
__device__ __forceinline__ float bits2f(unsigned short u) {
  return __uint_as_float(((unsigned)u) << 16);
}
__device__ __forceinline__ unsigned short f2bits(float x) {
  union { bf16 h; unsigned short u; } bu;
  bu.h = __float2bfloat16(x);
  return bu.u;
}
__device__ __forceinline__ float ldA(const float* A, size_t i) { return A[i]; }
__device__ __forceinline__ float ldA(const bf16* A, size_t i) { return __bfloat162float(A[i]); }

// ---------------- edge index normalize (handles int64 or int32 input) -------
__global__ __launch_bounds__(256)
void convert_edges(const int* __restrict__ ei, int* __restrict__ esrc,
                   int* __restrict__ edst, int E) {
  int e = blockIdx.x * 256 + threadIdx.x;
  if (e >= E) return;
  // int64 little-endian with values < 2^31 -> every odd int32 word is 0
  bool i64 = (ei[1] == 0) && (ei[3] == 0) && (ei[5] == 0) && (ei[7] == 0);
  int s, d;
  if (i64) { s = ei[2 * (size_t)e]; d = ei[2 * ((size_t)E + e)]; }
  else     { s = ei[e];             d = ei[E + e]; }
  esrc[e] = s; edst[e] = d;
}

// ---------------- CSR build (dst-sorted, self-loops appended) ---------------
__global__ __launch_bounds__(256)
void count_kernel(const int* __restrict__ edst, int* __restrict__ counts, int N, int E) {
  int e = blockIdx.x * 256 + threadIdx.x;
  int Etot = E + N;
  if (e >= Etot) return;
  int d = e < E ? edst[e] : e - E;
  atomicAdd(&counts[d], 1);
}

__global__ __launch_bounds__(1024)
void scan_kernel(const int* __restrict__ counts, int* __restrict__ row_ptr,
                 int* __restrict__ cursor, int N, int Etot) {
  __shared__ int sums[1024];
  int t = threadIdx.x;
  int chunk = (N + 1023) / 1024;
  int lo = t * chunk, hi = min(lo + chunk, N);
  int s = 0;
  for (int i = lo; i < hi; ++i) s += counts[i];
  sums[t] = s;
  __syncthreads();
  if (t == 0) {
    int run = 0;
#pragma unroll 1
    for (int i = 0; i < 1024; ++i) { int v = sums[i]; sums[i] = run; run += v; }
  }
  __syncthreads();
  int run = sums[t];
  for (int i = lo; i < hi; ++i) { row_ptr[i] = run; cursor[i] = run; run += counts[i]; }
  if (t == 0) row_ptr[N] = Etot;
}

__global__ __launch_bounds__(256)
void scatter_kernel(const int* __restrict__ esrc, const int* __restrict__ edst,
                    int* __restrict__ cursor, int* __restrict__ col, int N, int E) {
  int e = blockIdx.x * 256 + threadIdx.x;
  int Etot = E + N;
  if (e >= Etot) return;
  int s = e < E ? esrc[e] : e - E;
  int d = e < E ? edst[e] : e - E;
  int pos = atomicAdd(&cursor[d], 1);
  col[pos] = s;
}

// ---------------- tiled GEMM: C_bf16[M,N] = A[M,K] @ B_f32[K,N] -------------
#define BM 64
#define BN 64
#define BK 16
template <typename TA>
__global__ __launch_bounds__(256)
void gemm_bf16out(const TA* __restrict__ A, const float* __restrict__ B,
                  bf16* __restrict__ C, int M, int N, int K) {
  __shared__ float As[BK][BM + 1];
  __shared__ float Bs[BK][BN + 1];
  const int tid = threadIdx.x;
  const int tx = tid & 15, ty = tid >> 4;
  const int row0 = blockIdx.x * BM, col0 = blockIdx.y * BN;
  float acc[4][4] = {};
  for (int k0 = 0; k0 < K; k0 += BK) {
#pragma unroll
    for (int i = 0; i < 4; ++i) {           // A tile: BM x BK
      int idx = tid + i * 256;
      int m = idx >> 4, k = idx & 15;
      float v = 0.f;
      int gm = row0 + m, gk = k0 + k;
      if (gm < M && gk < K) v = ldA(A, (size_t)gm * K + gk);
      As[k][m] = v;
    }
#pragma unroll
    for (int i = 0; i < 4; ++i) {           // B tile: BK x BN
      int idx = tid + i * 256;
      int k = idx >> 6, n = idx & 63;
      float v = 0.f;
      int gk = k0 + k, gn = col0 + n;
      if (gk < K && gn < N) v = B[(size_t)gk * N + gn];
      Bs[k][n] = v;
    }
    __syncthreads();
#pragma unroll
    for (int k = 0; k < BK; ++k) {
      float a[4], b[4];
#pragma unroll
      for (int i = 0; i < 4; ++i) a[i] = As[k][ty * 4 + i];
#pragma unroll
      for (int j = 0; j < 4; ++j) b[j] = Bs[k][tx * 4 + j];
#pragma unroll
      for (int i = 0; i < 4; ++i)
#pragma unroll
        for (int j = 0; j < 4; ++j) acc[i][j] = fmaf(a[i], b[j], acc[i][j]);
    }
    __syncthreads();
  }
#pragma unroll
  for (int i = 0; i < 4; ++i) {
    int gm = row0 + ty * 4 + i;
    if (gm >= M) continue;
#pragma unroll
    for (int j = 0; j < 4; ++j) {
      int gn = col0 + tx * 4 + j;
      if (gn < N) C[(size_t)gm * N + gn] = __float2bfloat16(acc[i][j]);
    }
  }
}

// ---------------- alpha_s / alpha_d: one wave per (node, head) --------------
__global__ __launch_bounds__(256)
void alpha_kernel(const bf16* __restrict__ hbuf, const float* __restrict__ as,
                  const float* __restrict__ ad, float* __restrict__ alpha_s,
                  float* __restrict__ alpha_d, int NH) {
  int wid = (blockIdx.x * 256 + threadIdx.x) >> 6;
  int lane = threadIdx.x & 63;
  if (wid >= NH) return;
  int n = wid >> 3, h = wid & 7;
  float v = __bfloat162float(hbuf[(size_t)n * HF + h * HID + lane]);
  float s = wsum64(v * as[h * HID + lane]);
  float d = wsum64(v * ad[h * HID + lane]);
  if (lane == 0) { alpha_s[wid] = s; alpha_d[wid] = d; }
}

// ---------------- per-(node,head) softmax stats via CSR ---------------------
__global__ __launch_bounds__(256)
void stats_kernel(const int* __restrict__ row_ptr, const int* __restrict__ col,
                  const float* __restrict__ alpha_s, const float* __restrict__ alpha_d,
                  float* __restrict__ mbuf, float* __restrict__ invbuf, int N) {
  int t = blockIdx.x * 256 + threadIdx.x;
  if (t >= N * HEADS) return;
  int n = t >> 3, h = t & 7;
  float ad = alpha_d[t];
  int lo = row_ptr[n], hi = row_ptr[n + 1];
  float mx = -1e30f;
  for (int j = lo; j < hi; ++j)
    mx = fmaxf(mx, leaky(alpha_s[col[j] * HEADS + h] + ad));
  float s = 0.f;
  for (int j = lo; j < hi; ++j)
    s += __expf(leaky(alpha_s[col[j] * HEADS + h] + ad) - mx);
  mbuf[t] = mx;
  invbuf[t] = 1.f / s;   // deg >= 1 (self-loop) so s > 0
}

// ---------------- fused aggregate + epilogue --------------------------------
// one block of 128 threads per node; thread t owns features [4t, 4t+3], head t>>4
template <int LAYER>
__global__ __launch_bounds__(128)
void aggregate_kernel(const int* __restrict__ row_ptr, const int* __restrict__ col,
                      const bf16* __restrict__ hbuf,
                      const float* __restrict__ alpha_s, const float* __restrict__ alpha_d,
                      const float* __restrict__ mbuf, const float* __restrict__ invbuf,
                      const bf16* __restrict__ resid,
                      const float* __restrict__ bias, const float* __restrict__ g,
                      const float* __restrict__ b,
                      bf16* __restrict__ out_bf,     // layers 0,1 ([N,512]) ; layer 2 ([N,64])
                      int N) {
  int n = blockIdx.x;
  int t = threadIdx.x;
  int h = t >> 4;
  int nh = n * HEADS + h;
  float mh = mbuf[nh], inv = invbuf[nh], adh = alpha_d[nh];
  float a0 = 0.f, a1 = 0.f, a2 = 0.f, a3 = 0.f;
  int lo = row_ptr[n], hi = row_ptr[n + 1];
  for (int j = lo; j < hi; ++j) {
    int s = col[j];
    float al = __expf(leaky(alpha_s[s * HEADS + h] + adh) - mh) * inv;
    ushort4 u = *reinterpret_cast<const ushort4*>(hbuf + (size_t)s * HF + t * 4);
    a0 = fmaf(al, bits2f(u.x), a0);
    a1 = fmaf(al, bits2f(u.y), a1);
    a2 = fmaf(al, bits2f(u.z), a2);
    a3 = fmaf(al, bits2f(u.w), a3);
  }
  if (LAYER < 2) {
    float4 bb = ((const float4*)bias)[t];
    a0 += bb.x; a1 += bb.y; a2 += bb.z; a3 += bb.w;
    if (LAYER == 1) {
      ushort4 r = *reinterpret_cast<const ushort4*>(resid + (size_t)n * HF + t * 4);
      a0 += bits2f(r.x); a1 += bits2f(r.y); a2 += bits2f(r.z); a3 += bits2f(r.w);
    }
    float s = a0 + a1 + a2 + a3;
    float ss = a0 * a0 + a1 * a1 + a2 * a2 + a3 * a3;
    s = wsum64(s); ss = wsum64(ss);
    __shared__ float sh[4];
    if ((t & 63) == 0) { sh[t >> 6] = s; sh[2 + (t >> 6)] = ss; }
    __syncthreads();
    float tot = sh[0] + sh[1], tot2 = sh[2] + sh[3];
    float mu = tot * (1.f / HF);
    float var = tot2 * (1.f / HF) - mu * mu;
    float rs = rsqrtf(var + LN_EPS);
    float4 gg = ((const float4*)g)[t];
    float4 be = ((const float4*)b)[t];
    a0 = fmaxf((a0 - mu) * rs * gg.x + be.x, 0.f);
    a1 = fmaxf((a1 - mu) * rs * gg.y + be.y, 0.f);
    a2 = fmaxf((a2 - mu) * rs * gg.z + be.z, 0.f);
    a3 = fmaxf((a3 - mu) * rs * gg.w + be.w, 0.f);
    ushort4 o;
    o.x = f2bits(a0); o.y = f2bits(a1); o.z = f2bits(a2); o.w = f2bits(a3);
    *reinterpret_cast<ushort4*>(out_bf + (size_t)n * HF + t * 4) = o;
  } else {
    __shared__ float lds[HF];
    lds[t * 4 + 0] = a0; lds[t * 4 + 1] = a1;
    lds[t * 4 + 2] = a2; lds[t * 4 + 3] = a3;
    __syncthreads();
    if (t < HID) {
      float v = 0.f;
#pragma unroll
      for (int hh = 0; hh < HEADS; ++hh) v += lds[hh * HID + t];
      v = v * (1.f / HEADS) + bias[t];
      float s = wsum64(v);
      float ss = wsum64(v * v);
      float mu = s * (1.f / HID);
      float var = ss * (1.f / HID) - mu * mu;
      float rs = rsqrtf(var + LN_EPS);
      v = fmaxf((v - mu) * rs * g[t] + b[t], 0.f);
      out_bf[(size_t)n * HID + t] = __float2bfloat16(v);
    }
  }
}

// ---------------- final linear: [N,64]bf16 @ [64,2] + b ---------------------
__global__ __launch_bounds__(256)
void final_linear_kernel(const bf16* __restrict__ D, const float* __restrict__ w,
                         const float* __restrict__ bb, float* __restrict__ out, int N) {
  int wid = (blockIdx.x * 256 + threadIdx.x) >> 6;
  int lane = threadIdx.x & 63;
  if (wid >= N) return;
  float v = __bfloat162float(D[(size_t)wid * HID + lane]);
  float s0 = wsum64(v * w[lane * 2 + 0]);
  float s1 = wsum64(v * w[lane * 2 + 1]);
  if (lane == 0) {
    out[(size_t)wid * 2 + 0] = s0 + bb[0];
    out[(size_t)wid * 2 + 1] = s1 + bb[1];
  }
}

// ===========================================================================
extern "C" void kernel_launch(void* const* d_in, const int* in_sizes, int n_in,
                              void* d_out, int out_size, void* d_ws, size_t ws_size,
                              hipStream_t stream) {
  const float* x  = (const float*)d_in[0];
  const int*   ei = (const int*)d_in[1];
  const int N = in_sizes[0] / 165;       // 50000
  const int E = in_sizes[1] / 2;         // 400000
  const int Etot = E + N;

  const float* W[3]  = {(const float*)d_in[2],  (const float*)d_in[8],  (const float*)d_in[14]};
  const float* As[3] = {(const float*)d_in[3],  (const float*)d_in[9],  (const float*)d_in[15]};
  const float* Ad[3] = {(const float*)d_in[4],  (const float*)d_in[10], (const float*)d_in[16]};
  const float* Bi[3] = {(const float*)d_in[5],  (const float*)d_in[11], (const float*)d_in[17]};
  const float* Lg[3] = {(const float*)d_in[6],  (const float*)d_in[12], (const float*)d_in[18]};
  const float* Lb[3] = {(const float*)d_in[7],  (const float*)d_in[13], (const float*)d_in[19]};
  const float* lin_w = (const float*)d_in[20];
  const float* lin_b = (const float*)d_in[21];

  // ---- workspace carve-up (~121 MB total) ----
  char* p = (char*)d_ws;
  auto alloc = [&](size_t bytes) {
    char* r = p;
    p += (bytes + 255) & ~(size_t)255;
    return r;
  };
  bf16* feat0   = (bf16*)alloc((size_t)N * HF * 2);   // 51.2 MB (layer outputs, reused)
  bf16* hbuf    = (bf16*)alloc((size_t)N * HF * 2);   // 51.2 MB (transformed features)
  bf16* bufD    = (bf16*)alloc((size_t)N * HID * 2);  //  6.4 MB
  float* alpha_s = (float*)alloc((size_t)N * HEADS * 4);
  float* alpha_d = (float*)alloc((size_t)N * HEADS * 4);
  float* mbuf    = (float*)alloc((size_t)N * HEADS * 4);
  float* invbuf  = (float*)alloc((size_t)N * HEADS * 4);
  int* esrc    = (int*)alloc((size_t)E * 4);
  int* edst    = (int*)alloc((size_t)E * 4);
  int* counts  = (int*)alloc((size_t)N * 4);
  int* row_ptr = (int*)alloc((size_t)(N + 1) * 4);
  int* cursor  = (int*)alloc((size_t)N * 4);
  int* col     = (int*)alloc((size_t)Etot * 4);
  (void)ws_size;

  const int NH = N * HEADS;

  // ---- edge normalize + CSR build (once per call) ----
  convert_edges<<<(E + 255) / 256, 256, 0, stream>>>(ei, esrc, edst, E);
  hipMemsetAsync(counts, 0, (size_t)N * 4, stream);
  count_kernel<<<(Etot + 255) / 256, 256, 0, stream>>>(edst, counts, N, E);
  scan_kernel<<<1, 1024, 0, stream>>>(counts, row_ptr, cursor, N, Etot);
  scatter_kernel<<<(Etot + 255) / 256, 256, 0, stream>>>(esrc, edst, cursor, col, N, E);

  dim3 ggrid((N + BM - 1) / BM, HF / BN);
  const int nhBlocks   = (NH + 3) / 4;
  const int stBlocks   = (NH + 255) / 256;
  const int waveBlocks = (N + 3) / 4;

  // ---- layer 0: x(f32,165) -> feat0 ----
  gemm_bf16out<float><<<ggrid, 256, 0, stream>>>(x, W[0], hbuf, N, HF, 165);
  alpha_kernel<<<nhBlocks, 256, 0, stream>>>(hbuf, As[0], Ad[0], alpha_s, alpha_d, NH);
  stats_kernel<<<stBlocks, 256, 0, stream>>>(row_ptr, col, alpha_s, alpha_d, mbuf, invbuf, N);
  aggregate_kernel<0><<<N, 128, 0, stream>>>(row_ptr, col, hbuf, alpha_s, alpha_d,
                                             mbuf, invbuf, nullptr,
                                             Bi[0], Lg[0], Lb[0], feat0, N);

  // ---- layer 1: feat0 -> feat0 (in-place; residual read precedes write) ----
  gemm_bf16out<bf16><<<ggrid, 256, 0, stream>>>(feat0, W[1], hbuf, N, HF, HF);
  alpha_kernel<<<nhBlocks, 256, 0, stream>>>(hbuf, As[1], Ad[1], alpha_s, alpha_d, NH);
  stats_kernel<<<stBlocks, 256, 0, stream>>>(row_ptr, col, alpha_s, alpha_d, mbuf, invbuf, N);
  aggregate_kernel<1><<<N, 128, 0, stream>>>(row_ptr, col, hbuf, alpha_s, alpha_d,
                                             mbuf, invbuf, feat0,
                                             Bi[1], Lg[1], Lb[1], feat0, N);

  // ---- layer 2: feat0 -> bufD (head mean) ----
  gemm_bf16out<bf16><<<ggrid, 256, 0, stream>>>(feat0, W[2], hbuf, N, HF, HF);
  alpha_kernel<<<nhBlocks, 256, 0, stream>>>(hbuf, As[2], Ad[2], alpha_s, alpha_d, NH);
  stats_kernel<<<stBlocks, 256, 0, stream>>>(row_ptr, col, alpha_s, alpha_d, mbuf, invbuf, N);
  aggregate_kernel<2><<<N, 128, 0, stream>>>(row_ptr, col, hbuf, alpha_s, alpha_d,
                                             mbuf, invbuf, nullptr,
                                             Bi[2], Lg[2], Lb[2], bufD, N);

  final_linear_kernel<<<waveBlocks, 256, 0, stream>>>(bufD, lin_w, lin_b, (float*)d_out, N);
}

// Round 3
// 814.179 us; speedup vs baseline: 2.4359x; 2.4359x over previous
//
#include <hip/hip_runtime.h>
#include <hip/hip_bf16.h>
#include <cstdint>
#include <cstddef>

#define HEADS 8
#define HID 64
#define HF 512              // HEADS*HID
#define NEG_SLOPE 0.2f
#define LN_EPS 1e-5f

typedef __hip_bfloat16 bf16;
typedef __attribute__((ext_vector_type(8))) __bf16 bf16v8;
typedef __attribute__((ext_vector_type(4))) float f32x4;

// ---------------- helpers ---------------------------------------------------
__device__ __forceinline__ float wsum64(float v) {
#pragma unroll
  for (int o = 32; o > 0; o >>= 1) v += __shfl_xor(v, o, 64);
  return v;
}
__device__ __forceinline__ float leaky(float v) { return v >= 0.f ? v : NEG_SLOPE * v; }
__device__ __forceinline__ float bits2f(unsigned short u) {
  return __uint_as_float(((unsigned)u) << 16);
}
__device__ __forceinline__ unsigned short f2bits(float x) {
  union { bf16 h; unsigned short u; } bu;
  bu.h = __float2bfloat16(x);
  return bu.u;
}

// ---------------- edge index normalize (handles int64 or int32 input) -------
__global__ __launch_bounds__(256)
void convert_edges(const int* __restrict__ ei, int* __restrict__ esrc,
                   int* __restrict__ edst, int E) {
  int e = blockIdx.x * 256 + threadIdx.x;
  if (e >= E) return;
  bool i64 = (ei[1] == 0) && (ei[3] == 0) && (ei[5] == 0) && (ei[7] == 0);
  int s, d;
  if (i64) { s = ei[2 * (size_t)e]; d = ei[2 * ((size_t)E + e)]; }
  else     { s = ei[e];             d = ei[E + e]; }
  esrc[e] = s; edst[e] = d;
}

// ---------------- CSR build (dst-sorted, self-loops appended) ---------------
__global__ __launch_bounds__(256)
void count_kernel(const int* __restrict__ edst, int* __restrict__ counts, int N, int E) {
  int e = blockIdx.x * 256 + threadIdx.x;
  int Etot = E + N;
  if (e >= Etot) return;
  int d = e < E ? edst[e] : e - E;
  atomicAdd(&counts[d], 1);
}

__global__ __launch_bounds__(1024)
void scan_kernel(const int* __restrict__ counts, int* __restrict__ row_ptr,
                 int* __restrict__ cursor, int N, int Etot) {
  __shared__ int sums[1024];
  int t = threadIdx.x;
  int chunk = (N + 1023) / 1024;
  int lo = t * chunk, hi = min(lo + chunk, N);
  int s = 0;
  for (int i = lo; i < hi; ++i) s += counts[i];
  sums[t] = s;
  __syncthreads();
  if (t == 0) {
    int run = 0;
#pragma unroll 1
    for (int i = 0; i < 1024; ++i) { int v = sums[i]; sums[i] = run; run += v; }
  }
  __syncthreads();
  int run = sums[t];
  for (int i = lo; i < hi; ++i) { row_ptr[i] = run; cursor[i] = run; run += counts[i]; }
  if (t == 0) row_ptr[N] = Etot;
}

__global__ __launch_bounds__(256)
void scatter_kernel(const int* __restrict__ esrc, const int* __restrict__ edst,
                    int* __restrict__ cursor, int* __restrict__ col, int N, int E) {
  int e = blockIdx.x * 256 + threadIdx.x;
  int Etot = E + N;
  if (e >= Etot) return;
  int s = e < E ? esrc[e] : e - E;
  int d = e < E ? edst[e] : e - E;
  int pos = atomicAdd(&cursor[d], 1);
  col[pos] = s;
}

// ---------------- prep: x -> bf16 padded; W -> W^T bf16 padded ---------------
__global__ __launch_bounds__(256)
void convert_pad_x(const float* __restrict__ x, bf16* __restrict__ xbf,
                   int M, int K, int Kp) {
  int idx = blockIdx.x * 256 + threadIdx.x;
  if (idx >= M * Kp) return;
  int row = idx / Kp, colk = idx - row * Kp;
  float v = colk < K ? x[(size_t)row * K + colk] : 0.f;
  xbf[idx] = __float2bfloat16(v);
}

__global__ __launch_bounds__(256)
void transpose_w(const float* __restrict__ W, bf16* __restrict__ Wt,
                 int K, int Ncols, int Kp) {
  int idx = blockIdx.x * 256 + threadIdx.x;
  if (idx >= Ncols * Kp) return;
  int n = idx / Kp, k = idx - n * Kp;
  float v = k < K ? W[(size_t)k * Ncols + n] : 0.f;
  Wt[idx] = __float2bfloat16(v);
}

// ---------------- MFMA GEMM: C[M,512] = A[M,K](bf16) @ Bt[512,K](bf16)^T ----
// 128x128 tile, BK=32, 4 waves (2x2), each wave 64x64 via 4x4 frags of 16x16x32
#define LDSW 40   // LDS row stride in shorts (32 data + 8 pad, 80B: 16B-aligned)
__global__ __launch_bounds__(256)
void gemm_mfma(const bf16* __restrict__ A, const bf16* __restrict__ Bt,
               bf16* __restrict__ C, int M, int Ncols, int K) {
  __shared__ short Alds[128 * LDSW];
  __shared__ short Blds[128 * LDSW];
  const int tid = threadIdx.x;
  const int wave = tid >> 6, lane = tid & 63;
  const int wr = wave >> 1, wc = wave & 1;
  const int row0 = blockIdx.x * 128, col0 = blockIdx.y * 128;
  const int lrow = lane & 15;          // frag row (A) / col (B)
  const int kc = lane >> 4;            // k-chunk 0..3 (8 bf16 each)
  f32x4 acc[4][4] = {};

  for (int k0 = 0; k0 < K; k0 += 32) {
#pragma unroll
    for (int i = 0; i < 2; ++i) {     // stage 128x32 bf16 tiles (A and Bt)
      int idx = tid + i * 256;         // 0..511
      int r = idx >> 2, c4 = idx & 3;
      uint4 va = make_uint4(0, 0, 0, 0);
      int gm = row0 + r;
      if (gm < M) va = *reinterpret_cast<const uint4*>(A + (size_t)gm * K + k0 + c4 * 8);
      *reinterpret_cast<uint4*>(&Alds[r * LDSW + c4 * 8]) = va;
      uint4 vb = *reinterpret_cast<const uint4*>(Bt + (size_t)(col0 + r) * K + k0 + c4 * 8);
      *reinterpret_cast<uint4*>(&Blds[r * LDSW + c4 * 8]) = vb;
    }
    __syncthreads();
    bf16v8 af[4], bfr[4];
#pragma unroll
    for (int r = 0; r < 4; ++r)
      af[r] = *reinterpret_cast<const bf16v8*>(&Alds[(wr * 64 + r * 16 + lrow) * LDSW + kc * 8]);
#pragma unroll
    for (int c = 0; c < 4; ++c)
      bfr[c] = *reinterpret_cast<const bf16v8*>(&Blds[(wc * 64 + c * 16 + lrow) * LDSW + kc * 8]);
#pragma unroll
    for (int r = 0; r < 4; ++r)
#pragma unroll
      for (int c = 0; c < 4; ++c)
        acc[r][c] = __builtin_amdgcn_mfma_f32_16x16x32_bf16(af[r], bfr[c], acc[r][c], 0, 0, 0);
    __syncthreads();
  }

  // epilogue: C/D layout col=lane&15, row=(lane>>4)*4+j  [m89]
  const int crow = (lane >> 4) * 4;
  const int ccol = lane & 15;
#pragma unroll
  for (int r = 0; r < 4; ++r) {
#pragma unroll
    for (int c = 0; c < 4; ++c) {
      int gc = col0 + wc * 64 + c * 16 + ccol;
#pragma unroll
      for (int j = 0; j < 4; ++j) {
        int gr = row0 + wr * 64 + r * 16 + crow + j;
        if (gr < M) C[(size_t)gr * Ncols + gc] = __float2bfloat16(acc[r][c][j]);
      }
    }
  }
}

// ---------------- alpha_s / alpha_d: one wave per (node, head) --------------
__global__ __launch_bounds__(256)
void alpha_kernel(const bf16* __restrict__ hbuf, const float* __restrict__ as,
                  const float* __restrict__ ad, float* __restrict__ alpha_s,
                  float* __restrict__ alpha_d, int NH) {
  int wid = (blockIdx.x * 256 + threadIdx.x) >> 6;
  int lane = threadIdx.x & 63;
  if (wid >= NH) return;
  int n = wid >> 3, h = wid & 7;
  float v = __bfloat162float(hbuf[(size_t)n * HF + h * HID + lane]);
  float s = wsum64(v * as[h * HID + lane]);
  float d = wsum64(v * ad[h * HID + lane]);
  if (lane == 0) { alpha_s[wid] = s; alpha_d[wid] = d; }
}

// ---------------- per-(node,head) softmax stats via CSR ---------------------
__global__ __launch_bounds__(256)
void stats_kernel(const int* __restrict__ row_ptr, const int* __restrict__ col,
                  const float* __restrict__ alpha_s, const float* __restrict__ alpha_d,
                  float* __restrict__ mbuf, float* __restrict__ invbuf, int N) {
  int t = blockIdx.x * 256 + threadIdx.x;
  if (t >= N * HEADS) return;
  int n = t >> 3, h = t & 7;
  float ad = alpha_d[t];
  int lo = row_ptr[n], hi = row_ptr[n + 1];
  float mx = -1e30f;
  for (int j = lo; j < hi; ++j)
    mx = fmaxf(mx, leaky(alpha_s[col[j] * HEADS + h] + ad));
  float s = 0.f;
  for (int j = lo; j < hi; ++j)
    s += __expf(leaky(alpha_s[col[j] * HEADS + h] + ad) - mx);
  mbuf[t] = mx;
  invbuf[t] = 1.f / s;
}

// ---------------- fused aggregate + epilogue --------------------------------
template <int LAYER>
__global__ __launch_bounds__(128)
void aggregate_kernel(const int* __restrict__ row_ptr, const int* __restrict__ col,
                      const bf16* __restrict__ hbuf,
                      const float* __restrict__ alpha_s, const float* __restrict__ alpha_d,
                      const float* __restrict__ mbuf, const float* __restrict__ invbuf,
                      const bf16* __restrict__ resid,
                      const float* __restrict__ bias, const float* __restrict__ g,
                      const float* __restrict__ b,
                      bf16* __restrict__ out_bf, int N) {
  int n = blockIdx.x;
  int t = threadIdx.x;
  int h = t >> 4;
  int nh = n * HEADS + h;
  float mh = mbuf[nh], inv = invbuf[nh], adh = alpha_d[nh];
  float a0 = 0.f, a1 = 0.f, a2 = 0.f, a3 = 0.f;
  int lo = row_ptr[n], hi = row_ptr[n + 1];
  for (int j = lo; j < hi; ++j) {
    int s = col[j];
    float al = __expf(leaky(alpha_s[s * HEADS + h] + adh) - mh) * inv;
    ushort4 u = *reinterpret_cast<const ushort4*>(hbuf + (size_t)s * HF + t * 4);
    a0 = fmaf(al, bits2f(u.x), a0);
    a1 = fmaf(al, bits2f(u.y), a1);
    a2 = fmaf(al, bits2f(u.z), a2);
    a3 = fmaf(al, bits2f(u.w), a3);
  }
  if (LAYER < 2) {
    float4 bb = ((const float4*)bias)[t];
    a0 += bb.x; a1 += bb.y; a2 += bb.z; a3 += bb.w;
    if (LAYER == 1) {
      ushort4 r = *reinterpret_cast<const ushort4*>(resid + (size_t)n * HF + t * 4);
      a0 += bits2f(r.x); a1 += bits2f(r.y); a2 += bits2f(r.z); a3 += bits2f(r.w);
    }
    float s = a0 + a1 + a2 + a3;
    float ss = a0 * a0 + a1 * a1 + a2 * a2 + a3 * a3;
    s = wsum64(s); ss = wsum64(ss);
    __shared__ float sh[4];
    if ((t & 63) == 0) { sh[t >> 6] = s; sh[2 + (t >> 6)] = ss; }
    __syncthreads();
    float tot = sh[0] + sh[1], tot2 = sh[2] + sh[3];
    float mu = tot * (1.f / HF);
    float var = tot2 * (1.f / HF) - mu * mu;
    float rs = rsqrtf(var + LN_EPS);
    float4 gg = ((const float4*)g)[t];
    float4 be = ((const float4*)b)[t];
    a0 = fmaxf((a0 - mu) * rs * gg.x + be.x, 0.f);
    a1 = fmaxf((a1 - mu) * rs * gg.y + be.y, 0.f);
    a2 = fmaxf((a2 - mu) * rs * gg.z + be.z, 0.f);
    a3 = fmaxf((a3 - mu) * rs * gg.w + be.w, 0.f);
    ushort4 o;
    o.x = f2bits(a0); o.y = f2bits(a1); o.z = f2bits(a2); o.w = f2bits(a3);
    *reinterpret_cast<ushort4*>(out_bf + (size_t)n * HF + t * 4) = o;
  } else {
    __shared__ float lds[HF];
    lds[t * 4 + 0] = a0; lds[t * 4 + 1] = a1;
    lds[t * 4 + 2] = a2; lds[t * 4 + 3] = a3;
    __syncthreads();
    if (t < HID) {
      float v = 0.f;
#pragma unroll
      for (int hh = 0; hh < HEADS; ++hh) v += lds[hh * HID + t];
      v = v * (1.f / HEADS) + bias[t];
      float s = wsum64(v);
      float ss = wsum64(v * v);
      float mu = s * (1.f / HID);
      float var = ss * (1.f / HID) - mu * mu;
      float rs = rsqrtf(var + LN_EPS);
      v = fmaxf((v - mu) * rs * g[t] + b[t], 0.f);
      out_bf[(size_t)n * HID + t] = __float2bfloat16(v);
    }
  }
}

// ---------------- final linear: [N,64]bf16 @ [64,2] + b ---------------------
__global__ __launch_bounds__(256)
void final_linear_kernel(const bf16* __restrict__ D, const float* __restrict__ w,
                         const float* __restrict__ bb, float* __restrict__ out, int N) {
  int wid = (blockIdx.x * 256 + threadIdx.x) >> 6;
  int lane = threadIdx.x & 63;
  if (wid >= N) return;
  float v = __bfloat162float(D[(size_t)wid * HID + lane]);
  float s0 = wsum64(v * w[lane * 2 + 0]);
  float s1 = wsum64(v * w[lane * 2 + 1]);
  if (lane == 0) {
    out[(size_t)wid * 2 + 0] = s0 + bb[0];
    out[(size_t)wid * 2 + 1] = s1 + bb[1];
  }
}

// ===========================================================================
extern "C" void kernel_launch(void* const* d_in, const int* in_sizes, int n_in,
                              void* d_out, int out_size, void* d_ws, size_t ws_size,
                              hipStream_t stream) {
  const float* x  = (const float*)d_in[0];
  const int*   ei = (const int*)d_in[1];
  const int N = in_sizes[0] / 165;       // 50000
  const int E = in_sizes[1] / 2;         // 400000
  const int Etot = E + N;
  const int K0P = 192;                   // layer-0 K padded (165 -> 192)

  const float* W[3]  = {(const float*)d_in[2],  (const float*)d_in[8],  (const float*)d_in[14]};
  const float* As[3] = {(const float*)d_in[3],  (const float*)d_in[9],  (const float*)d_in[15]};
  const float* Ad[3] = {(const float*)d_in[4],  (const float*)d_in[10], (const float*)d_in[16]};
  const float* Bi[3] = {(const float*)d_in[5],  (const float*)d_in[11], (const float*)d_in[17]};
  const float* Lg[3] = {(const float*)d_in[6],  (const float*)d_in[12], (const float*)d_in[18]};
  const float* Lb[3] = {(const float*)d_in[7],  (const float*)d_in[13], (const float*)d_in[19]};
  const float* lin_w = (const float*)d_in[20];
  const float* lin_b = (const float*)d_in[21];

  // ---- workspace carve-up (~123 MB total) ----
  char* p = (char*)d_ws;
  auto alloc = [&](size_t bytes) {
    char* r = p;
    p += (bytes + 255) & ~(size_t)255;
    return r;
  };
  bf16* feat0   = (bf16*)alloc((size_t)N * HF * 2);   // layer outputs; ALSO aliases xbf
  bf16* hbuf    = (bf16*)alloc((size_t)N * HF * 2);   // transformed features
  bf16* bufD    = (bf16*)alloc((size_t)N * HID * 2);
  float* alpha_s = (float*)alloc((size_t)N * HEADS * 4);
  float* alpha_d = (float*)alloc((size_t)N * HEADS * 4);
  float* mbuf    = (float*)alloc((size_t)N * HEADS * 4);
  float* invbuf  = (float*)alloc((size_t)N * HEADS * 4);
  bf16* W0t = (bf16*)alloc((size_t)HF * K0P * 2);
  bf16* W1t = (bf16*)alloc((size_t)HF * HF * 2);
  bf16* W2t = (bf16*)alloc((size_t)HF * HF * 2);
  int* esrc    = (int*)alloc((size_t)E * 4);
  int* edst    = (int*)alloc((size_t)E * 4);
  int* counts  = (int*)alloc((size_t)N * 4);
  int* row_ptr = (int*)alloc((size_t)(N + 1) * 4);
  int* cursor  = (int*)alloc((size_t)N * 4);
  int* col     = (int*)alloc((size_t)Etot * 4);
  (void)ws_size;

  bf16* xbf = feat0;   // dead before aggregate<0> writes feat0

  const int NH = N * HEADS;

  // ---- edge normalize + CSR build ----
  convert_edges<<<(E + 255) / 256, 256, 0, stream>>>(ei, esrc, edst, E);
  hipMemsetAsync(counts, 0, (size_t)N * 4, stream);
  count_kernel<<<(Etot + 255) / 256, 256, 0, stream>>>(edst, counts, N, E);
  scan_kernel<<<1, 1024, 0, stream>>>(counts, row_ptr, cursor, N, Etot);
  scatter_kernel<<<(Etot + 255) / 256, 256, 0, stream>>>(esrc, edst, cursor, col, N, E);

  // ---- prep: bf16 conversions / transposes ----
  convert_pad_x<<<((N * K0P) + 255) / 256, 256, 0, stream>>>(x, xbf, N, 165, K0P);
  transpose_w<<<((HF * K0P) + 255) / 256, 256, 0, stream>>>(W[0], W0t, 165, HF, K0P);
  transpose_w<<<((HF * HF) + 255) / 256, 256, 0, stream>>>(W[1], W1t, HF, HF, HF);
  transpose_w<<<((HF * HF) + 255) / 256, 256, 0, stream>>>(W[2], W2t, HF, HF, HF);

  dim3 ggrid((N + 127) / 128, HF / 128);
  const int nhBlocks   = (NH + 3) / 4;
  const int stBlocks   = (NH + 255) / 256;
  const int waveBlocks = (N + 3) / 4;

  // ---- layer 0 ----
  gemm_mfma<<<ggrid, 256, 0, stream>>>(xbf, W0t, hbuf, N, HF, K0P);
  alpha_kernel<<<nhBlocks, 256, 0, stream>>>(hbuf, As[0], Ad[0], alpha_s, alpha_d, NH);
  stats_kernel<<<stBlocks, 256, 0, stream>>>(row_ptr, col, alpha_s, alpha_d, mbuf, invbuf, N);
  aggregate_kernel<0><<<N, 128, 0, stream>>>(row_ptr, col, hbuf, alpha_s, alpha_d,
                                             mbuf, invbuf, nullptr,
                                             Bi[0], Lg[0], Lb[0], feat0, N);

  // ---- layer 1 (in-place residual) ----
  gemm_mfma<<<ggrid, 256, 0, stream>>>(feat0, W1t, hbuf, N, HF, HF);
  alpha_kernel<<<nhBlocks, 256, 0, stream>>>(hbuf, As[1], Ad[1], alpha_s, alpha_d, NH);
  stats_kernel<<<stBlocks, 256, 0, stream>>>(row_ptr, col, alpha_s, alpha_d, mbuf, invbuf, N);
  aggregate_kernel<1><<<N, 128, 0, stream>>>(row_ptr, col, hbuf, alpha_s, alpha_d,
                                             mbuf, invbuf, feat0,
                                             Bi[1], Lg[1], Lb[1], feat0, N);

  // ---- layer 2 (head mean) ----
  gemm_mfma<<<ggrid, 256, 0, stream>>>(feat0, W2t, hbuf, N, HF, HF);
  alpha_kernel<<<nhBlocks, 256, 0, stream>>>(hbuf, As[2], Ad[2], alpha_s, alpha_d, NH);
  stats_kernel<<<stBlocks, 256, 0, stream>>>(row_ptr, col, alpha_s, alpha_d, mbuf, invbuf, N);
  aggregate_kernel<2><<<N, 128, 0, stream>>>(row_ptr, col, hbuf, alpha_s, alpha_d,
                                             mbuf, invbuf, nullptr,
                                             Bi[2], Lg[2], Lb[2], bufD, N);

  final_linear_kernel<<<waveBlocks, 256, 0, stream>>>(bufD, lin_w, lin_b, (float*)d_out, N);
}

// Round 4
// 680.726 us; speedup vs baseline: 2.9134x; 1.1960x over previous
//
#include <hip/hip_runtime.h>
#include <hip/hip_bf16.h>
#include <cstdint>
#include <cstddef>

#define HEADS 8
#define HID 64
#define HF 512              // HEADS*HID
#define NEG_SLOPE 0.2f
#define LN_EPS 1e-5f

typedef __hip_bfloat16 bf16;
typedef __attribute__((ext_vector_type(8))) __bf16 bf16v8;
typedef __attribute__((ext_vector_type(4))) float f32x4;

// ---------------- helpers ---------------------------------------------------
__device__ __forceinline__ float wsum64(float v) {
#pragma unroll
  for (int o = 32; o > 0; o >>= 1) v += __shfl_xor(v, o, 64);
  return v;
}
__device__ __forceinline__ int wsum64i(int v) {
#pragma unroll
  for (int o = 32; o > 0; o >>= 1) v += __shfl_xor(v, o, 64);
  return v;
}
__device__ __forceinline__ float leaky(float v) { return v >= 0.f ? v : NEG_SLOPE * v; }
__device__ __forceinline__ float bits2f(unsigned short u) {
  return __uint_as_float(((unsigned)u) << 16);
}
__device__ __forceinline__ unsigned short f2bits(float x) {
  union { bf16 h; unsigned short u; } bu;
  bu.h = __float2bfloat16(x);
  return bu.u;
}

// ---------------- edge normalize + count (handles int64 or int32) -----------
__global__ __launch_bounds__(256)
void convert_count(const int* __restrict__ ei, int* __restrict__ esrc,
                   int* __restrict__ edst, int* __restrict__ counts, int E) {
  int e = blockIdx.x * 256 + threadIdx.x;
  if (e >= E) return;
  bool i64 = (ei[1] == 0) && (ei[3] == 0) && (ei[5] == 0) && (ei[7] == 0);
  int s, d;
  if (i64) { s = ei[2 * (size_t)e]; d = ei[2 * ((size_t)E + e)]; }
  else     { s = ei[e];             d = ei[E + e]; }
  esrc[e] = s; edst[e] = d;
  atomicAdd(&counts[d], 1);
}

// ---------------- hierarchical exclusive scan over (counts[i]+1) ------------
// degree(i) = counts[i] + 1 (self-loop). N <= 64*1024 assumed.
#define SCAN_T 256
#define SCAN_EPT 4
#define SCAN_CHUNK (SCAN_T * SCAN_EPT)   // 1024

__global__ __launch_bounds__(SCAN_T)
void scan_pass1(const int* __restrict__ counts, int* __restrict__ bsum, int N) {
  int b = blockIdx.x, t = threadIdx.x;
  int base = b * SCAN_CHUNK + t * SCAN_EPT;
  int s = 0;
#pragma unroll
  for (int i = 0; i < SCAN_EPT; ++i) {
    int idx = base + i;
    if (idx < N) s += counts[idx] + 1;
  }
  int lane = t & 63, w = t >> 6;
  int tot = wsum64i(s);
  __shared__ int ws[4];
  if (lane == 0) ws[w] = tot;
  __syncthreads();
  if (t == 0) bsum[b] = ws[0] + ws[1] + ws[2] + ws[3];
}

__global__ __launch_bounds__(64)
void scan_pass2(const int* __restrict__ bsum, int* __restrict__ boff, int NB) {
  int t = threadIdx.x;
  int own = t < NB ? bsum[t] : 0;
  int v = own;
#pragma unroll
  for (int o = 1; o < 64; o <<= 1) {
    int u = __shfl_up(v, o, 64);
    if (t >= o) v += u;
  }
  if (t < NB) boff[t] = v - own;   // exclusive
}

__global__ __launch_bounds__(SCAN_T)
void scan_pass3(const int* __restrict__ counts, const int* __restrict__ boff,
                int* __restrict__ row_ptr, int* __restrict__ cursor, int N, int Etot) {
  int b = blockIdx.x, t = threadIdx.x;
  int base = b * SCAN_CHUNK + t * SCAN_EPT;
  int c[SCAN_EPT];
  int s = 0;
#pragma unroll
  for (int i = 0; i < SCAN_EPT; ++i) {
    int idx = base + i;
    c[i] = idx < N ? counts[idx] + 1 : 0;
    s += c[i];
  }
  int lane = t & 63, w = t >> 6;
  int inc = s;
#pragma unroll
  for (int o = 1; o < 64; o <<= 1) {
    int u = __shfl_up(inc, o, 64);
    if (lane >= o) inc += u;
  }
  __shared__ int wsums[4];
  if (lane == 63) wsums[w] = inc;
  __syncthreads();
  int woff = 0;
  for (int i = 0; i < w; ++i) woff += wsums[i];
  int run = inc - s + woff + boff[b];
#pragma unroll
  for (int i = 0; i < SCAN_EPT; ++i) {
    int idx = base + i;
    if (idx < N) { row_ptr[idx] = run; cursor[idx] = run; run += c[i]; }
  }
  if (b == 0 && t == 0) row_ptr[N] = Etot;
}

__global__ __launch_bounds__(256)
void scatter_kernel(const int* __restrict__ esrc, const int* __restrict__ edst,
                    int* __restrict__ cursor, int* __restrict__ col, int N, int E) {
  int e = blockIdx.x * 256 + threadIdx.x;
  int Etot = E + N;
  if (e >= Etot) return;
  int s = e < E ? esrc[e] : e - E;
  int d = e < E ? edst[e] : e - E;
  int pos = atomicAdd(&cursor[d], 1);
  col[pos] = s;
}

// ---------------- prep: x -> bf16 padded; W -> W^T bf16 padded ---------------
__global__ __launch_bounds__(256)
void convert_pad_x(const float* __restrict__ x, bf16* __restrict__ xbf,
                   int M, int K, int Kp) {
  int idx = blockIdx.x * 256 + threadIdx.x;
  if (idx >= M * Kp) return;
  int row = idx / Kp, colk = idx - row * Kp;
  float v = colk < K ? x[(size_t)row * K + colk] : 0.f;
  xbf[idx] = __float2bfloat16(v);
}

__global__ __launch_bounds__(256)
void transpose_w(const float* __restrict__ W, bf16* __restrict__ Wt,
                 int K, int Ncols, int Kp) {
  int idx = blockIdx.x * 256 + threadIdx.x;
  if (idx >= Ncols * Kp) return;
  int n = idx / Kp, k = idx - n * Kp;
  float v = k < K ? W[(size_t)k * Ncols + n] : 0.f;
  Wt[idx] = __float2bfloat16(v);
}

// ---------------- MFMA GEMM: C[M,512] = A[M,K](bf16) @ Bt[512,K](bf16)^T ----
#define LDSW 40   // LDS row stride in shorts (32 data + 8 pad, 80B: 16B-aligned)
__global__ __launch_bounds__(256)
void gemm_mfma(const bf16* __restrict__ A, const bf16* __restrict__ Bt,
               bf16* __restrict__ C, int M, int Ncols, int K) {
  __shared__ short Alds[128 * LDSW];
  __shared__ short Blds[128 * LDSW];
  const int tid = threadIdx.x;
  const int wave = tid >> 6, lane = tid & 63;
  const int wr = wave >> 1, wc = wave & 1;
  const int row0 = blockIdx.x * 128, col0 = blockIdx.y * 128;
  const int lrow = lane & 15;
  const int kc = lane >> 4;
  f32x4 acc[4][4] = {};

  for (int k0 = 0; k0 < K; k0 += 32) {
#pragma unroll
    for (int i = 0; i < 2; ++i) {
      int idx = tid + i * 256;
      int r = idx >> 2, c4 = idx & 3;
      uint4 va = make_uint4(0, 0, 0, 0);
      int gm = row0 + r;
      if (gm < M) va = *reinterpret_cast<const uint4*>(A + (size_t)gm * K + k0 + c4 * 8);
      *reinterpret_cast<uint4*>(&Alds[r * LDSW + c4 * 8]) = va;
      uint4 vb = *reinterpret_cast<const uint4*>(Bt + (size_t)(col0 + r) * K + k0 + c4 * 8);
      *reinterpret_cast<uint4*>(&Blds[r * LDSW + c4 * 8]) = vb;
    }
    __syncthreads();
    bf16v8 af[4], bfr[4];
#pragma unroll
    for (int r = 0; r < 4; ++r)
      af[r] = *reinterpret_cast<const bf16v8*>(&Alds[(wr * 64 + r * 16 + lrow) * LDSW + kc * 8]);
#pragma unroll
    for (int c = 0; c < 4; ++c)
      bfr[c] = *reinterpret_cast<const bf16v8*>(&Blds[(wc * 64 + c * 16 + lrow) * LDSW + kc * 8]);
#pragma unroll
    for (int r = 0; r < 4; ++r)
#pragma unroll
      for (int c = 0; c < 4; ++c)
        acc[r][c] = __builtin_amdgcn_mfma_f32_16x16x32_bf16(af[r], bfr[c], acc[r][c], 0, 0, 0);
    __syncthreads();
  }

  const int crow = (lane >> 4) * 4;
  const int ccol = lane & 15;
#pragma unroll
  for (int r = 0; r < 4; ++r) {
#pragma unroll
    for (int c = 0; c < 4; ++c) {
      int gc = col0 + wc * 64 + c * 16 + ccol;
#pragma unroll
      for (int j = 0; j < 4; ++j) {
        int gr = row0 + wr * 64 + r * 16 + crow + j;
        if (gr < M) C[(size_t)gr * Ncols + gc] = __float2bfloat16(acc[r][c][j]);
      }
    }
  }
}

// ---------------- alpha_s / alpha_d: one wave per (node, head) --------------
__global__ __launch_bounds__(256)
void alpha_kernel(const bf16* __restrict__ hbuf, const float* __restrict__ as,
                  const float* __restrict__ ad, float* __restrict__ alpha_s,
                  float* __restrict__ alpha_d, int NH) {
  int wid = (blockIdx.x * 256 + threadIdx.x) >> 6;
  int lane = threadIdx.x & 63;
  if (wid >= NH) return;
  int n = wid >> 3, h = wid & 7;
  float v = __bfloat162float(hbuf[(size_t)n * HF + h * HID + lane]);
  float s = wsum64(v * as[h * HID + lane]);
  float d = wsum64(v * ad[h * HID + lane]);
  if (lane == 0) { alpha_s[wid] = s; alpha_d[wid] = d; }
}

// ---------------- per-(node,head) softmax stats via CSR ---------------------
__global__ __launch_bounds__(256)
void stats_kernel(const int* __restrict__ row_ptr, const int* __restrict__ col,
                  const float* __restrict__ alpha_s, const float* __restrict__ alpha_d,
                  float* __restrict__ mbuf, float* __restrict__ invbuf, int N) {
  int t = blockIdx.x * 256 + threadIdx.x;
  if (t >= N * HEADS) return;
  int n = t >> 3, h = t & 7;
  float ad = alpha_d[t];
  int lo = row_ptr[n], hi = row_ptr[n + 1];
  float mx = -1e30f;
  for (int j = lo; j < hi; ++j)
    mx = fmaxf(mx, leaky(alpha_s[col[j] * HEADS + h] + ad));
  float s = 0.f;
  for (int j = lo; j < hi; ++j)
    s += __expf(leaky(alpha_s[col[j] * HEADS + h] + ad) - mx);
  mbuf[t] = mx;
  invbuf[t] = 1.f / s;
}

// ---------------- fused aggregate + epilogue --------------------------------
template <int LAYER>
__global__ __launch_bounds__(128)
void aggregate_kernel(const int* __restrict__ row_ptr, const int* __restrict__ col,
                      const bf16* __restrict__ hbuf,
                      const float* __restrict__ alpha_s, const float* __restrict__ alpha_d,
                      const float* __restrict__ mbuf, const float* __restrict__ invbuf,
                      const bf16* __restrict__ resid,
                      const float* __restrict__ bias, const float* __restrict__ g,
                      const float* __restrict__ b,
                      bf16* __restrict__ out_bf, int N) {
  int n = blockIdx.x;
  int t = threadIdx.x;
  int h = t >> 4;
  int nh = n * HEADS + h;
  float mh = mbuf[nh], inv = invbuf[nh], adh = alpha_d[nh];
  float a0 = 0.f, a1 = 0.f, a2 = 0.f, a3 = 0.f;
  int lo = row_ptr[n], hi = row_ptr[n + 1];
  for (int j = lo; j < hi; ++j) {
    int s = col[j];
    float al = __expf(leaky(alpha_s[s * HEADS + h] + adh) - mh) * inv;
    ushort4 u = *reinterpret_cast<const ushort4*>(hbuf + (size_t)s * HF + t * 4);
    a0 = fmaf(al, bits2f(u.x), a0);
    a1 = fmaf(al, bits2f(u.y), a1);
    a2 = fmaf(al, bits2f(u.z), a2);
    a3 = fmaf(al, bits2f(u.w), a3);
  }
  if (LAYER < 2) {
    float4 bb = ((const float4*)bias)[t];
    a0 += bb.x; a1 += bb.y; a2 += bb.z; a3 += bb.w;
    if (LAYER == 1) {
      ushort4 r = *reinterpret_cast<const ushort4*>(resid + (size_t)n * HF + t * 4);
      a0 += bits2f(r.x); a1 += bits2f(r.y); a2 += bits2f(r.z); a3 += bits2f(r.w);
    }
    float s = a0 + a1 + a2 + a3;
    float ss = a0 * a0 + a1 * a1 + a2 * a2 + a3 * a3;
    s = wsum64(s); ss = wsum64(ss);
    __shared__ float sh[4];
    if ((t & 63) == 0) { sh[t >> 6] = s; sh[2 + (t >> 6)] = ss; }
    __syncthreads();
    float tot = sh[0] + sh[1], tot2 = sh[2] + sh[3];
    float mu = tot * (1.f / HF);
    float var = tot2 * (1.f / HF) - mu * mu;
    float rs = rsqrtf(var + LN_EPS);
    float4 gg = ((const float4*)g)[t];
    float4 be = ((const float4*)b)[t];
    a0 = fmaxf((a0 - mu) * rs * gg.x + be.x, 0.f);
    a1 = fmaxf((a1 - mu) * rs * gg.y + be.y, 0.f);
    a2 = fmaxf((a2 - mu) * rs * gg.z + be.z, 0.f);
    a3 = fmaxf((a3 - mu) * rs * gg.w + be.w, 0.f);
    ushort4 o;
    o.x = f2bits(a0); o.y = f2bits(a1); o.z = f2bits(a2); o.w = f2bits(a3);
    *reinterpret_cast<ushort4*>(out_bf + (size_t)n * HF + t * 4) = o;
  } else {
    __shared__ float lds[HF];
    lds[t * 4 + 0] = a0; lds[t * 4 + 1] = a1;
    lds[t * 4 + 2] = a2; lds[t * 4 + 3] = a3;
    __syncthreads();
    if (t < HID) {
      float v = 0.f;
#pragma unroll
      for (int hh = 0; hh < HEADS; ++hh) v += lds[hh * HID + t];
      v = v * (1.f / HEADS) + bias[t];
      float s = wsum64(v);
      float ss = wsum64(v * v);
      float mu = s * (1.f / HID);
      float var = ss * (1.f / HID) - mu * mu;
      float rs = rsqrtf(var + LN_EPS);
      v = fmaxf((v - mu) * rs * g[t] + b[t], 0.f);
      out_bf[(size_t)n * HID + t] = __float2bfloat16(v);
    }
  }
}

// ---------------- final linear: [N,64]bf16 @ [64,2] + b ---------------------
__global__ __launch_bounds__(256)
void final_linear_kernel(const bf16* __restrict__ D, const float* __restrict__ w,
                         const float* __restrict__ bb, float* __restrict__ out, int N) {
  int wid = (blockIdx.x * 256 + threadIdx.x) >> 6;
  int lane = threadIdx.x & 63;
  if (wid >= N) return;
  float v = __bfloat162float(D[(size_t)wid * HID + lane]);
  float s0 = wsum64(v * w[lane * 2 + 0]);
  float s1 = wsum64(v * w[lane * 2 + 1]);
  if (lane == 0) {
    out[(size_t)wid * 2 + 0] = s0 + bb[0];
    out[(size_t)wid * 2 + 1] = s1 + bb[1];
  }
}

// ===========================================================================
extern "C" void kernel_launch(void* const* d_in, const int* in_sizes, int n_in,
                              void* d_out, int out_size, void* d_ws, size_t ws_size,
                              hipStream_t stream) {
  const float* x  = (const float*)d_in[0];
  const int*   ei = (const int*)d_in[1];
  const int N = in_sizes[0] / 165;       // 50000
  const int E = in_sizes[1] / 2;         // 400000
  const int Etot = E + N;
  const int K0P = 192;

  const float* W[3]  = {(const float*)d_in[2],  (const float*)d_in[8],  (const float*)d_in[14]};
  const float* As[3] = {(const float*)d_in[3],  (const float*)d_in[9],  (const float*)d_in[15]};
  const float* Ad[3] = {(const float*)d_in[4],  (const float*)d_in[10], (const float*)d_in[16]};
  const float* Bi[3] = {(const float*)d_in[5],  (const float*)d_in[11], (const float*)d_in[17]};
  const float* Lg[3] = {(const float*)d_in[6],  (const float*)d_in[12], (const float*)d_in[18]};
  const float* Lb[3] = {(const float*)d_in[7],  (const float*)d_in[13], (const float*)d_in[19]};
  const float* lin_w = (const float*)d_in[20];
  const float* lin_b = (const float*)d_in[21];

  // ---- workspace carve-up ----
  char* p = (char*)d_ws;
  auto alloc = [&](size_t bytes) {
    char* r = p;
    p += (bytes + 255) & ~(size_t)255;
    return r;
  };
  bf16* feat0   = (bf16*)alloc((size_t)N * HF * 2);   // layer outputs; aliases xbf
  bf16* hbuf    = (bf16*)alloc((size_t)N * HF * 2);
  bf16* bufD    = (bf16*)alloc((size_t)N * HID * 2);
  float* alpha_s = (float*)alloc((size_t)N * HEADS * 4);
  float* alpha_d = (float*)alloc((size_t)N * HEADS * 4);
  float* mbuf    = (float*)alloc((size_t)N * HEADS * 4);
  float* invbuf  = (float*)alloc((size_t)N * HEADS * 4);
  bf16* W0t = (bf16*)alloc((size_t)HF * K0P * 2);
  bf16* W1t = (bf16*)alloc((size_t)HF * HF * 2);
  bf16* W2t = (bf16*)alloc((size_t)HF * HF * 2);
  int* esrc    = (int*)alloc((size_t)E * 4);
  int* edst    = (int*)alloc((size_t)E * 4);
  int* counts  = (int*)alloc((size_t)N * 4);
  int* row_ptr = (int*)alloc((size_t)(N + 1) * 4);
  int* cursor  = (int*)alloc((size_t)N * 4);
  int* col     = (int*)alloc((size_t)Etot * 4);
  int* bsum    = (int*)alloc((size_t)256 * 4);
  int* boff    = (int*)alloc((size_t)256 * 4);
  (void)ws_size;

  bf16* xbf = feat0;   // dead before aggregate<0> writes feat0

  const int NH = N * HEADS;
  const int NB = (N + SCAN_CHUNK - 1) / SCAN_CHUNK;   // 49 (<=64)

  // ---- edge normalize + CSR build ----
  hipMemsetAsync(counts, 0, (size_t)N * 4, stream);
  convert_count<<<(E + 255) / 256, 256, 0, stream>>>(ei, esrc, edst, counts, E);
  scan_pass1<<<NB, SCAN_T, 0, stream>>>(counts, bsum, N);
  scan_pass2<<<1, 64, 0, stream>>>(bsum, boff, NB);
  scan_pass3<<<NB, SCAN_T, 0, stream>>>(counts, boff, row_ptr, cursor, N, Etot);
  scatter_kernel<<<(Etot + 255) / 256, 256, 0, stream>>>(esrc, edst, cursor, col, N, E);

  // ---- prep: bf16 conversions / transposes ----
  convert_pad_x<<<((N * K0P) + 255) / 256, 256, 0, stream>>>(x, xbf, N, 165, K0P);
  transpose_w<<<((HF * K0P) + 255) / 256, 256, 0, stream>>>(W[0], W0t, 165, HF, K0P);
  transpose_w<<<((HF * HF) + 255) / 256, 256, 0, stream>>>(W[1], W1t, HF, HF, HF);
  transpose_w<<<((HF * HF) + 255) / 256, 256, 0, stream>>>(W[2], W2t, HF, HF, HF);

  dim3 ggrid((N + 127) / 128, HF / 128);
  const int nhBlocks   = (NH + 3) / 4;
  const int stBlocks   = (NH + 255) / 256;
  const int waveBlocks = (N + 3) / 4;

  // ---- layer 0 ----
  gemm_mfma<<<ggrid, 256, 0, stream>>>(xbf, W0t, hbuf, N, HF, K0P);
  alpha_kernel<<<nhBlocks, 256, 0, stream>>>(hbuf, As[0], Ad[0], alpha_s, alpha_d, NH);
  stats_kernel<<<stBlocks, 256, 0, stream>>>(row_ptr, col, alpha_s, alpha_d, mbuf, invbuf, N);
  aggregate_kernel<0><<<N, 128, 0, stream>>>(row_ptr, col, hbuf, alpha_s, alpha_d,
                                             mbuf, invbuf, nullptr,
                                             Bi[0], Lg[0], Lb[0], feat0, N);

  // ---- layer 1 (in-place residual) ----
  gemm_mfma<<<ggrid, 256, 0, stream>>>(feat0, W1t, hbuf, N, HF, HF);
  alpha_kernel<<<nhBlocks, 256, 0, stream>>>(hbuf, As[1], Ad[1], alpha_s, alpha_d, NH);
  stats_kernel<<<stBlocks, 256, 0, stream>>>(row_ptr, col, alpha_s, alpha_d, mbuf, invbuf, N);
  aggregate_kernel<1><<<N, 128, 0, stream>>>(row_ptr, col, hbuf, alpha_s, alpha_d,
                                             mbuf, invbuf, feat0,
                                             Bi[1], Lg[1], Lb[1], feat0, N);

  // ---- layer 2 (head mean) ----
  gemm_mfma<<<ggrid, 256, 0, stream>>>(feat0, W2t, hbuf, N, HF, HF);
  alpha_kernel<<<nhBlocks, 256, 0, stream>>>(hbuf, As[2], Ad[2], alpha_s, alpha_d, NH);
  stats_kernel<<<stBlocks, 256, 0, stream>>>(row_ptr, col, alpha_s, alpha_d, mbuf, invbuf, N);
  aggregate_kernel<2><<<N, 128, 0, stream>>>(row_ptr, col, hbuf, alpha_s, alpha_d,
                                             mbuf, invbuf, nullptr,
                                             Bi[2], Lg[2], Lb[2], bufD, N);

  final_linear_kernel<<<waveBlocks, 256, 0, stream>>>(bufD, lin_w, lin_b, (float*)d_out, N);
}

// Round 5
// 512.769 us; speedup vs baseline: 3.8677x; 1.3275x over previous
//
#include <hip/hip_runtime.h>
#include <hip/hip_bf16.h>
#include <cstdint>
#include <cstddef>

#define HEADS 8
#define HID 64
#define HF 512              // HEADS*HID
#define NEG_SLOPE 0.2f
#define LN_EPS 1e-5f

typedef __hip_bfloat16 bf16;
typedef __attribute__((ext_vector_type(8))) __bf16 bf16v8;
typedef __attribute__((ext_vector_type(4))) float f32x4;

// ---------------- helpers ---------------------------------------------------
__device__ __forceinline__ float wsum64(float v) {
#pragma unroll
  for (int o = 32; o > 0; o >>= 1) v += __shfl_xor(v, o, 64);
  return v;
}
__device__ __forceinline__ int wsum64i(int v) {
#pragma unroll
  for (int o = 32; o > 0; o >>= 1) v += __shfl_xor(v, o, 64);
  return v;
}
__device__ __forceinline__ float leaky(float v) { return v >= 0.f ? v : NEG_SLOPE * v; }
__device__ __forceinline__ float bits2f(unsigned short u) {
  return __uint_as_float(((unsigned)u) << 16);
}
__device__ __forceinline__ unsigned short f2bits(float x) {
  union { bf16 h; unsigned short u; } bu;
  bu.h = __float2bfloat16(x);
  return bu.u;
}

// ---------------- edge normalize + count (handles int64 or int32) -----------
__global__ __launch_bounds__(256)
void convert_count(const int* __restrict__ ei, int* __restrict__ esrc,
                   int* __restrict__ edst, int* __restrict__ counts, int E) {
  int e = blockIdx.x * 256 + threadIdx.x;
  if (e >= E) return;
  bool i64 = (ei[1] == 0) && (ei[3] == 0) && (ei[5] == 0) && (ei[7] == 0);
  int s, d;
  if (i64) { s = ei[2 * (size_t)e]; d = ei[2 * ((size_t)E + e)]; }
  else     { s = ei[e];             d = ei[E + e]; }
  esrc[e] = s; edst[e] = d;
  atomicAdd(&counts[d], 1);
}

// ---------------- hierarchical exclusive scan over (counts[i]+1) ------------
#define SCAN_T 256
#define SCAN_EPT 4
#define SCAN_CHUNK (SCAN_T * SCAN_EPT)   // 1024

__global__ __launch_bounds__(SCAN_T)
void scan_pass1(const int* __restrict__ counts, int* __restrict__ bsum, int N) {
  int b = blockIdx.x, t = threadIdx.x;
  int base = b * SCAN_CHUNK + t * SCAN_EPT;
  int s = 0;
#pragma unroll
  for (int i = 0; i < SCAN_EPT; ++i) {
    int idx = base + i;
    if (idx < N) s += counts[idx] + 1;
  }
  int lane = t & 63, w = t >> 6;
  int tot = wsum64i(s);
  __shared__ int ws[4];
  if (lane == 0) ws[w] = tot;
  __syncthreads();
  if (t == 0) bsum[b] = ws[0] + ws[1] + ws[2] + ws[3];
}

__global__ __launch_bounds__(64)
void scan_pass2(const int* __restrict__ bsum, int* __restrict__ boff, int NB) {
  int t = threadIdx.x;
  int own = t < NB ? bsum[t] : 0;
  int v = own;
#pragma unroll
  for (int o = 1; o < 64; o <<= 1) {
    int u = __shfl_up(v, o, 64);
    if (t >= o) v += u;
  }
  if (t < NB) boff[t] = v - own;   // exclusive
}

__global__ __launch_bounds__(SCAN_T)
void scan_pass3(const int* __restrict__ counts, const int* __restrict__ boff,
                int* __restrict__ row_ptr, int* __restrict__ cursor, int N, int Etot) {
  int b = blockIdx.x, t = threadIdx.x;
  int base = b * SCAN_CHUNK + t * SCAN_EPT;
  int c[SCAN_EPT];
  int s = 0;
#pragma unroll
  for (int i = 0; i < SCAN_EPT; ++i) {
    int idx = base + i;
    c[i] = idx < N ? counts[idx] + 1 : 0;
    s += c[i];
  }
  int lane = t & 63, w = t >> 6;
  int inc = s;
#pragma unroll
  for (int o = 1; o < 64; o <<= 1) {
    int u = __shfl_up(inc, o, 64);
    if (lane >= o) inc += u;
  }
  __shared__ int wsums[4];
  if (lane == 63) wsums[w] = inc;
  __syncthreads();
  int woff = 0;
  for (int i = 0; i < w; ++i) woff += wsums[i];
  int run = inc - s + woff + boff[b];
#pragma unroll
  for (int i = 0; i < SCAN_EPT; ++i) {
    int idx = base + i;
    if (idx < N) { row_ptr[idx] = run; cursor[idx] = run; run += c[i]; }
  }
  if (b == 0 && t == 0) row_ptr[N] = Etot;
}

__global__ __launch_bounds__(256)
void scatter_kernel(const int* __restrict__ esrc, const int* __restrict__ edst,
                    int* __restrict__ cursor, int* __restrict__ col, int N, int E) {
  int e = blockIdx.x * 256 + threadIdx.x;
  int Etot = E + N;
  if (e >= Etot) return;
  int s = e < E ? esrc[e] : e - E;
  int d = e < E ? edst[e] : e - E;
  int pos = atomicAdd(&cursor[d], 1);
  col[pos] = s;
}

// ---------------- prep: x -> bf16 padded; W -> W^T bf16 padded ---------------
__global__ __launch_bounds__(256)
void convert_pad_x(const float* __restrict__ x, bf16* __restrict__ xbf,
                   int M, int K, int Kp) {
  int idx = blockIdx.x * 256 + threadIdx.x;
  if (idx >= M * Kp) return;
  int row = idx / Kp, colk = idx - row * Kp;
  float v = colk < K ? x[(size_t)row * K + colk] : 0.f;
  xbf[idx] = __float2bfloat16(v);
}

__global__ __launch_bounds__(256)
void transpose_w(const float* __restrict__ W, bf16* __restrict__ Wt,
                 int K, int Ncols, int Kp) {
  int idx = blockIdx.x * 256 + threadIdx.x;
  if (idx >= Ncols * Kp) return;
  int n = idx / Kp, k = idx - n * Kp;
  float v = k < K ? W[(size_t)k * Ncols + n] : 0.f;
  Wt[idx] = __float2bfloat16(v);
}

// ---------------- MFMA GEMM: C[M,512] = A[M,K](bf16) @ Bt[512,K](bf16)^T ----
#define LDSW 40   // LDS row stride in shorts (32 data + 8 pad, 80B: 16B-aligned)
__global__ __launch_bounds__(256)
void gemm_mfma(const bf16* __restrict__ A, const bf16* __restrict__ Bt,
               bf16* __restrict__ C, int M, int Ncols, int K) {
  __shared__ short Alds[128 * LDSW];
  __shared__ short Blds[128 * LDSW];
  const int tid = threadIdx.x;
  const int wave = tid >> 6, lane = tid & 63;
  const int wr = wave >> 1, wc = wave & 1;
  const int row0 = blockIdx.x * 128, col0 = blockIdx.y * 128;
  const int lrow = lane & 15;
  const int kc = lane >> 4;
  f32x4 acc[4][4] = {};

  for (int k0 = 0; k0 < K; k0 += 32) {
#pragma unroll
    for (int i = 0; i < 2; ++i) {
      int idx = tid + i * 256;
      int r = idx >> 2, c4 = idx & 3;
      uint4 va = make_uint4(0, 0, 0, 0);
      int gm = row0 + r;
      if (gm < M) va = *reinterpret_cast<const uint4*>(A + (size_t)gm * K + k0 + c4 * 8);
      *reinterpret_cast<uint4*>(&Alds[r * LDSW + c4 * 8]) = va;
      uint4 vb = *reinterpret_cast<const uint4*>(Bt + (size_t)(col0 + r) * K + k0 + c4 * 8);
      *reinterpret_cast<uint4*>(&Blds[r * LDSW + c4 * 8]) = vb;
    }
    __syncthreads();
    bf16v8 af[4], bfr[4];
#pragma unroll
    for (int r = 0; r < 4; ++r)
      af[r] = *reinterpret_cast<const bf16v8*>(&Alds[(wr * 64 + r * 16 + lrow) * LDSW + kc * 8]);
#pragma unroll
    for (int c = 0; c < 4; ++c)
      bfr[c] = *reinterpret_cast<const bf16v8*>(&Blds[(wc * 64 + c * 16 + lrow) * LDSW + kc * 8]);
#pragma unroll
    for (int r = 0; r < 4; ++r)
#pragma unroll
      for (int c = 0; c < 4; ++c)
        acc[r][c] = __builtin_amdgcn_mfma_f32_16x16x32_bf16(af[r], bfr[c], acc[r][c], 0, 0, 0);
    __syncthreads();
  }

  const int crow = (lane >> 4) * 4;
  const int ccol = lane & 15;
#pragma unroll
  for (int r = 0; r < 4; ++r) {
#pragma unroll
    for (int c = 0; c < 4; ++c) {
      int gc = col0 + wc * 64 + c * 16 + ccol;
#pragma unroll
      for (int j = 0; j < 4; ++j) {
        int gr = row0 + wr * 64 + r * 16 + crow + j;
        if (gr < M) C[(size_t)gr * Ncols + gc] = __float2bfloat16(acc[r][c][j]);
      }
    }
  }
}

// ---------------- alpha_s / alpha_d: one wave per NODE ----------------------
// lane loads 8 bf16 (16B); 8-lane group = one head; shfl reduce within group
__global__ __launch_bounds__(256)
void alpha_kernel(const bf16* __restrict__ hbuf, const float* __restrict__ as,
                  const float* __restrict__ ad, float* __restrict__ alpha_s,
                  float* __restrict__ alpha_d, int N) {
  int wid = (blockIdx.x * 256 + threadIdx.x) >> 6;
  int lane = threadIdx.x & 63;
  if (wid >= N) return;
  ushort4 u0 = *reinterpret_cast<const ushort4*>(hbuf + (size_t)wid * HF + lane * 8);
  ushort4 u1 = *reinterpret_cast<const ushort4*>(hbuf + (size_t)wid * HF + lane * 8 + 4);
  float4 s0 = ((const float4*)as)[lane * 2], s1 = ((const float4*)as)[lane * 2 + 1];
  float4 d0 = ((const float4*)ad)[lane * 2], d1 = ((const float4*)ad)[lane * 2 + 1];
  float f0 = bits2f(u0.x), f1 = bits2f(u0.y), f2 = bits2f(u0.z), f3 = bits2f(u0.w);
  float f4 = bits2f(u1.x), f5 = bits2f(u1.y), f6 = bits2f(u1.z), f7 = bits2f(u1.w);
  float s = f0 * s0.x + f1 * s0.y + f2 * s0.z + f3 * s0.w
          + f4 * s1.x + f5 * s1.y + f6 * s1.z + f7 * s1.w;
  float d = f0 * d0.x + f1 * d0.y + f2 * d0.z + f3 * d0.w
          + f4 * d1.x + f5 * d1.y + f6 * d1.z + f7 * d1.w;
#pragma unroll
  for (int o = 1; o < 8; o <<= 1) {
    s += __shfl_xor(s, o, 64);
    d += __shfl_xor(d, o, 64);
  }
  if ((lane & 7) == 0) {
    alpha_s[wid * HEADS + (lane >> 3)] = s;
    alpha_d[wid * HEADS + (lane >> 3)] = d;
  }
}

// ---------------- fused aggregate (ONLINE softmax) + epilogue ---------------
// one block of 128 threads per node; thread t owns features [4t,4t+3], head t>>4
// all 16 threads of a head-group compute identical (m, den) - no cross-lane needed
template <int LAYER>
__global__ __launch_bounds__(128)
void aggregate_kernel(const int* __restrict__ row_ptr, const int* __restrict__ col,
                      const bf16* __restrict__ hbuf,
                      const float* __restrict__ alpha_s, const float* __restrict__ alpha_d,
                      const bf16* __restrict__ resid,
                      const float* __restrict__ bias, const float* __restrict__ g,
                      const float* __restrict__ b,
                      bf16* __restrict__ out_bf, int N) {
  int n = blockIdx.x;
  int t = threadIdx.x;
  int h = t >> 4;
  float adh = alpha_d[n * HEADS + h];
  float m = -1e30f, den = 0.f;
  float a0 = 0.f, a1 = 0.f, a2 = 0.f, a3 = 0.f;
  int lo = row_ptr[n], hi = row_ptr[n + 1];

  // prefetched state for edge j
  int sj = col[lo];
  float asj = alpha_s[sj * HEADS + h];
  ushort4 u = *reinterpret_cast<const ushort4*>(hbuf + (size_t)sj * HF + t * 4);

  for (int j = lo; j < hi; ++j) {
    float e = leaky(asj + adh);
    ushort4 uc = u;
    if (j + 1 < hi) {                      // prefetch next edge
      int sn = col[j + 1];
      asj = alpha_s[sn * HEADS + h];
      u = *reinterpret_cast<const ushort4*>(hbuf + (size_t)sn * HF + t * 4);
    }
    if (e > m) {                           // online-softmax rescale
      float sc = __expf(m - e);
      den *= sc; a0 *= sc; a1 *= sc; a2 *= sc; a3 *= sc;
      m = e;
    }
    float ex = __expf(e - m);
    den += ex;
    a0 = fmaf(ex, bits2f(uc.x), a0);
    a1 = fmaf(ex, bits2f(uc.y), a1);
    a2 = fmaf(ex, bits2f(uc.z), a2);
    a3 = fmaf(ex, bits2f(uc.w), a3);
  }
  float inv = 1.f / den;
  a0 *= inv; a1 *= inv; a2 *= inv; a3 *= inv;

  if (LAYER < 2) {
    float4 bb = ((const float4*)bias)[t];
    a0 += bb.x; a1 += bb.y; a2 += bb.z; a3 += bb.w;
    if (LAYER == 1) {
      ushort4 r = *reinterpret_cast<const ushort4*>(resid + (size_t)n * HF + t * 4);
      a0 += bits2f(r.x); a1 += bits2f(r.y); a2 += bits2f(r.z); a3 += bits2f(r.w);
    }
    float s = a0 + a1 + a2 + a3;
    float ss = a0 * a0 + a1 * a1 + a2 * a2 + a3 * a3;
    s = wsum64(s); ss = wsum64(ss);
    __shared__ float sh[4];
    if ((t & 63) == 0) { sh[t >> 6] = s; sh[2 + (t >> 6)] = ss; }
    __syncthreads();
    float tot = sh[0] + sh[1], tot2 = sh[2] + sh[3];
    float mu = tot * (1.f / HF);
    float var = tot2 * (1.f / HF) - mu * mu;
    float rs = rsqrtf(var + LN_EPS);
    float4 gg = ((const float4*)g)[t];
    float4 be = ((const float4*)b)[t];
    a0 = fmaxf((a0 - mu) * rs * gg.x + be.x, 0.f);
    a1 = fmaxf((a1 - mu) * rs * gg.y + be.y, 0.f);
    a2 = fmaxf((a2 - mu) * rs * gg.z + be.z, 0.f);
    a3 = fmaxf((a3 - mu) * rs * gg.w + be.w, 0.f);
    ushort4 o;
    o.x = f2bits(a0); o.y = f2bits(a1); o.z = f2bits(a2); o.w = f2bits(a3);
    *reinterpret_cast<ushort4*>(out_bf + (size_t)n * HF + t * 4) = o;
  } else {
    __shared__ float lds[HF];
    lds[t * 4 + 0] = a0; lds[t * 4 + 1] = a1;
    lds[t * 4 + 2] = a2; lds[t * 4 + 3] = a3;
    __syncthreads();
    if (t < HID) {
      float v = 0.f;
#pragma unroll
      for (int hh = 0; hh < HEADS; ++hh) v += lds[hh * HID + t];
      v = v * (1.f / HEADS) + bias[t];
      float s = wsum64(v);
      float ss = wsum64(v * v);
      float mu = s * (1.f / HID);
      float var = ss * (1.f / HID) - mu * mu;
      float rs = rsqrtf(var + LN_EPS);
      v = fmaxf((v - mu) * rs * g[t] + b[t], 0.f);
      out_bf[(size_t)n * HID + t] = __float2bfloat16(v);
    }
  }
}

// ---------------- final linear: [N,64]bf16 @ [64,2] + b ---------------------
__global__ __launch_bounds__(256)
void final_linear_kernel(const bf16* __restrict__ D, const float* __restrict__ w,
                         const float* __restrict__ bb, float* __restrict__ out, int N) {
  int wid = (blockIdx.x * 256 + threadIdx.x) >> 6;
  int lane = threadIdx.x & 63;
  if (wid >= N) return;
  float v = __bfloat162float(D[(size_t)wid * HID + lane]);
  float s0 = wsum64(v * w[lane * 2 + 0]);
  float s1 = wsum64(v * w[lane * 2 + 1]);
  if (lane == 0) {
    out[(size_t)wid * 2 + 0] = s0 + bb[0];
    out[(size_t)wid * 2 + 1] = s1 + bb[1];
  }
}

// ===========================================================================
extern "C" void kernel_launch(void* const* d_in, const int* in_sizes, int n_in,
                              void* d_out, int out_size, void* d_ws, size_t ws_size,
                              hipStream_t stream) {
  const float* x  = (const float*)d_in[0];
  const int*   ei = (const int*)d_in[1];
  const int N = in_sizes[0] / 165;       // 50000
  const int E = in_sizes[1] / 2;         // 400000
  const int Etot = E + N;
  const int K0P = 192;

  const float* W[3]  = {(const float*)d_in[2],  (const float*)d_in[8],  (const float*)d_in[14]};
  const float* As[3] = {(const float*)d_in[3],  (const float*)d_in[9],  (const float*)d_in[15]};
  const float* Ad[3] = {(const float*)d_in[4],  (const float*)d_in[10], (const float*)d_in[16]};
  const float* Bi[3] = {(const float*)d_in[5],  (const float*)d_in[11], (const float*)d_in[17]};
  const float* Lg[3] = {(const float*)d_in[6],  (const float*)d_in[12], (const float*)d_in[18]};
  const float* Lb[3] = {(const float*)d_in[7],  (const float*)d_in[13], (const float*)d_in[19]};
  const float* lin_w = (const float*)d_in[20];
  const float* lin_b = (const float*)d_in[21];

  // ---- workspace carve-up ----
  char* p = (char*)d_ws;
  auto alloc = [&](size_t bytes) {
    char* r = p;
    p += (bytes + 255) & ~(size_t)255;
    return r;
  };
  bf16* feat0   = (bf16*)alloc((size_t)N * HF * 2);   // layer outputs; aliases xbf
  bf16* hbuf    = (bf16*)alloc((size_t)N * HF * 2);
  bf16* bufD    = (bf16*)alloc((size_t)N * HID * 2);
  float* alpha_s = (float*)alloc((size_t)N * HEADS * 4);
  float* alpha_d = (float*)alloc((size_t)N * HEADS * 4);
  bf16* W0t = (bf16*)alloc((size_t)HF * K0P * 2);
  bf16* W1t = (bf16*)alloc((size_t)HF * HF * 2);
  bf16* W2t = (bf16*)alloc((size_t)HF * HF * 2);
  int* esrc    = (int*)alloc((size_t)E * 4);
  int* edst    = (int*)alloc((size_t)E * 4);
  int* counts  = (int*)alloc((size_t)N * 4);
  int* row_ptr = (int*)alloc((size_t)(N + 1) * 4);
  int* cursor  = (int*)alloc((size_t)N * 4);
  int* col     = (int*)alloc((size_t)Etot * 4);
  int* bsum    = (int*)alloc((size_t)256 * 4);
  int* boff    = (int*)alloc((size_t)256 * 4);
  (void)ws_size;

  bf16* xbf = feat0;   // dead before aggregate<0> writes feat0

  const int NB = (N + SCAN_CHUNK - 1) / SCAN_CHUNK;   // 49 (<=64)

  // ---- edge normalize + CSR build ----
  hipMemsetAsync(counts, 0, (size_t)N * 4, stream);
  convert_count<<<(E + 255) / 256, 256, 0, stream>>>(ei, esrc, edst, counts, E);
  scan_pass1<<<NB, SCAN_T, 0, stream>>>(counts, bsum, N);
  scan_pass2<<<1, 64, 0, stream>>>(bsum, boff, NB);
  scan_pass3<<<NB, SCAN_T, 0, stream>>>(counts, boff, row_ptr, cursor, N, Etot);
  scatter_kernel<<<(Etot + 255) / 256, 256, 0, stream>>>(esrc, edst, cursor, col, N, E);

  // ---- prep: bf16 conversions / transposes ----
  convert_pad_x<<<((N * K0P) + 255) / 256, 256, 0, stream>>>(x, xbf, N, 165, K0P);
  transpose_w<<<((HF * K0P) + 255) / 256, 256, 0, stream>>>(W[0], W0t, 165, HF, K0P);
  transpose_w<<<((HF * HF) + 255) / 256, 256, 0, stream>>>(W[1], W1t, HF, HF, HF);
  transpose_w<<<((HF * HF) + 255) / 256, 256, 0, stream>>>(W[2], W2t, HF, HF, HF);

  dim3 ggrid((N + 127) / 128, HF / 128);
  const int waveBlocks = (N + 3) / 4;

  // ---- layer 0 ----
  gemm_mfma<<<ggrid, 256, 0, stream>>>(xbf, W0t, hbuf, N, HF, K0P);
  alpha_kernel<<<waveBlocks, 256, 0, stream>>>(hbuf, As[0], Ad[0], alpha_s, alpha_d, N);
  aggregate_kernel<0><<<N, 128, 0, stream>>>(row_ptr, col, hbuf, alpha_s, alpha_d,
                                             nullptr, Bi[0], Lg[0], Lb[0], feat0, N);

  // ---- layer 1 (in-place residual) ----
  gemm_mfma<<<ggrid, 256, 0, stream>>>(feat0, W1t, hbuf, N, HF, HF);
  alpha_kernel<<<waveBlocks, 256, 0, stream>>>(hbuf, As[1], Ad[1], alpha_s, alpha_d, N);
  aggregate_kernel<1><<<N, 128, 0, stream>>>(row_ptr, col, hbuf, alpha_s, alpha_d,
                                             feat0, Bi[1], Lg[1], Lb[1], feat0, N);

  // ---- layer 2 (head mean) ----
  gemm_mfma<<<ggrid, 256, 0, stream>>>(feat0, W2t, hbuf, N, HF, HF);
  alpha_kernel<<<waveBlocks, 256, 0, stream>>>(hbuf, As[2], Ad[2], alpha_s, alpha_d, N);
  aggregate_kernel<2><<<N, 128, 0, stream>>>(row_ptr, col, hbuf, alpha_s, alpha_d,
                                             nullptr, Bi[2], Lg[2], Lb[2], bufD, N);

  final_linear_kernel<<<waveBlocks, 256, 0, stream>>>(bufD, lin_w, lin_b, (float*)d_out, N);
}